// Round 8
// baseline (408.757 us; speedup 1.0000x reference)
//
#include <hip/hip_runtime.h>
#include <math.h>

#define N_POS 8192
#define BATCH 4
#define N_GT 512
#define BG 2048
#define EPSV 1e-6f

#define KA_BLOCKS 1024
#define ROWS_A 8
#define KC_BLOCKS 256
#define ROWS_C 32

// workspace float offsets
// dpack layout: dpack[n][j], j = gathered column; batch of column j = j>>9
#define WS_DPACK 0                              // [8192][2048] = 64 MiB
#define WS_PARTS (N_POS * BG)                   // [256][2048] = 2 MiB
#define WS_MIND  (WS_PARTS + KC_BLOCKS * BG)    // [8][8192] per-WAVE row mins (batch b = waves 2b,2b+1)
#define WS_MAXP  (WS_MIND + 8 * N_POS)          // [1024] kA block maxes
#define WS_SC    (WS_MAXP + KA_BLOCKS)          // [0]=maxd [1]=pmin [2]=prange [3..6]=n_est
                                                // [7..10]=t1 [11]=t2sum [12]=kD2 ticket

typedef __attribute__((ext_vector_type(4))) float f32x4;

// raw barrier: drain LDS writes only — global prefetch loads stay in flight (no vmcnt(0))
__device__ __forceinline__ void rowbar() {
    asm volatile("s_waitcnt lgkmcnt(0)" ::: "memory");
    __builtin_amdgcn_s_barrier();
    asm volatile("" ::: "memory");
}

// ---------------- kA: dis_matrix pass, DEPTH-4 prefetch, raw-barrier pipelined ----------------
__global__ __launch_bounds__(512) void whd_kA(const float* __restrict__ dis,
                                              const int* __restrict__ gt,
                                              float* __restrict__ wsf) {
    __shared__ float rowbuf[2][N_POS];  // 64 KB double buffer
    __shared__ float smax[8];
    const int t = threadIdx.x;
    const int wv = t >> 6, lane = t & 63;
    const int row0 = blockIdx.x * ROWS_A;
    float* dpack = wsf + WS_DPACK;
    float* minD2 = wsf + WS_MIND;

    // gt columns for this thread: coalesced 16B read, no LDS staging
    int c[4];
    {
        const int4 ci = ((const int4*)gt)[t];
        c[0] = ci.x; c[1] = ci.y; c[2] = ci.z; c[3] = ci.w;
    }

    // depth-4 prefetch: rows row0..row0+3 into 4 register banks
    f32x4 pre[4][4];
    #pragma unroll
    for (int b = 0; b < 4; b++) {
        const f32x4* s = (const f32x4*)(dis + (size_t)(row0 + b) * N_POS);
        #pragma unroll
        for (int j = 0; j < 4; j++) pre[b][j] = __builtin_nontemporal_load(s + t + 512 * j);
    }

    float tmax = -INFINITY;
    #pragma unroll
    for (int r = 0; r < ROWS_A; r++) {      // fully unrolled -> all indices static
        const int n = row0 + r;
        const int bk = r & 3;
        float* buf = rowbuf[r & 1];
        // stage row r into LDS (compiler inserts counted vmcnt for bank bk only), fold max
        #pragma unroll
        for (int j = 0; j < 4; j++) ((f32x4*)buf)[t + 512 * j] = pre[bk][j];
        #pragma unroll
        for (int j = 0; j < 4; j++)
            tmax = fmaxf(tmax, fmaxf(fmaxf(pre[bk][j].x, pre[bk][j].y),
                                     fmaxf(pre[bk][j].z, pre[bk][j].w)));
        // refill bank bk with row r+4 — 4 phases of slack covers ~900cy HBM latency
        if (r + 4 < ROWS_A) {
            const f32x4* sn = (const f32x4*)(dis + (size_t)(n + 4) * N_POS);
            #pragma unroll
            for (int j = 0; j < 4; j++) pre[bk][j] = __builtin_nontemporal_load(sn + t + 512 * j);
        }
        rowbar();   // LDS writes visible; prefetch loads remain in flight across the barrier
        // gather this thread's 4 gt-columns from LDS
        float g0 = buf[c[0]], g1 = buf[c[1]], g2 = buf[c[2]], g3 = buf[c[3]];
        f32x4 pk; pk.x = g0; pk.y = g1; pk.z = g2; pk.w = g3;
        ((f32x4*)(dpack + (size_t)n * BG + 4 * t))[0] = pk;
        // per-wave min over its 256 columns (wave wv covers half of batch wv>>1)
        float m = fminf(fminf(g0, g1), fminf(g2, g3));
        #pragma unroll
        for (int off = 32; off; off >>= 1) m = fminf(m, __shfl_xor(m, off, 64));
        if (lane == 0) minD2[(size_t)wv * N_POS + n] = m;
        // ping-pong safety: buf[r&1] rewritten at iter r+2, which is after barrier r+1;
        // any thread still gathering at iter r has not yet passed barrier r+1 -> ordered.
    }
    #pragma unroll
    for (int off = 32; off; off >>= 1) tmax = fmaxf(tmax, __shfl_down(tmax, off, 64));
    if (lane == 0) smax[wv] = tmax;
    __syncthreads();
    if (t == 0) {
        float m = smax[0];
        #pragma unroll
        for (int i = 1; i < 8; i++) m = fmaxf(m, smax[i]);
        wsf[WS_MAXP + blockIdx.x] = m;
    }
}

// ---------------- kB: finalize scalars + n_est/term1 (single block, shfl-reduced) ----------------
__global__ __launch_bounds__(1024) void whd_kB(const float* __restrict__ prob,
                                               float* __restrict__ wsf) {
    __shared__ float sA[16], sB[16], sC[16];
    const int t = threadIdx.x, wv = t >> 6, lane = t & 63;

    // maxdist over kA block maxes
    float m = -INFINITY;
    for (int i = t; i < KA_BLOCKS; i += 1024) m = fmaxf(m, wsf[WS_MAXP + i]);
    #pragma unroll
    for (int off = 32; off; off >>= 1) m = fmaxf(m, __shfl_xor(m, off, 64));

    // fused prob min/max, float4 loads
    float lmin = INFINITY, lmax = -INFINITY;
    const f32x4* p4 = (const f32x4*)prob;
    for (int i = t; i < BATCH * N_POS / 4; i += 1024) {
        f32x4 v = p4[i];
        lmin = fminf(fminf(lmin, fminf(v.x, v.y)), fminf(v.z, v.w));
        lmax = fmaxf(fmaxf(lmax, fmaxf(v.x, v.y)), fmaxf(v.z, v.w));
    }
    #pragma unroll
    for (int off = 32; off; off >>= 1) {
        lmin = fminf(lmin, __shfl_xor(lmin, off, 64));
        lmax = fmaxf(lmax, __shfl_xor(lmax, off, 64));
    }
    if (lane == 0) { sA[wv] = m; sB[wv] = lmin; sC[wv] = lmax; }
    __syncthreads();
    if (t == 0) {
        float maxd = -INFINITY, mn = INFINITY, mx = -INFINITY;
        #pragma unroll
        for (int i = 0; i < 16; i++) {
            maxd = fmaxf(maxd, sA[i]); mn = fminf(mn, sB[i]); mx = fmaxf(mx, sC[i]);
        }
        wsf[WS_SC + 0] = maxd;
        wsf[WS_SC + 1] = mn;
        wsf[WS_SC + 2] = mx - mn;
        wsf[WS_SC + 11] = 0.f;   // t2 accumulator
        wsf[WS_SC + 12] = 0.f;   // kD2 ticket
        sB[0] = mn; sC[0] = 1.0f / (mx - mn);
    }
    __syncthreads();
    const float pmin = sB[0], invr = sC[0];

    for (int b = 0; b < BATCH; b++) {
        const f32x4* dA = (const f32x4*)(wsf + WS_MIND + (size_t)(2 * b) * N_POS);
        const f32x4* dB = (const f32x4*)(wsf + WS_MIND + (size_t)(2 * b + 1) * N_POS);
        float sp = 0.f, spm = 0.f;
        for (int i = t; i < N_POS / 4; i += 1024) {
            f32x4 v = p4[b * (N_POS / 4) + i];
            f32x4 da = dA[i], db = dB[i];
            float p;
            p = fminf(fmaxf((v.x - pmin) * invr, 0.f), 1.f); sp += p; spm += p * fminf(da.x, db.x);
            p = fminf(fmaxf((v.y - pmin) * invr, 0.f), 1.f); sp += p; spm += p * fminf(da.y, db.y);
            p = fminf(fmaxf((v.z - pmin) * invr, 0.f), 1.f); sp += p; spm += p * fminf(da.z, db.z);
            p = fminf(fmaxf((v.w - pmin) * invr, 0.f), 1.f); sp += p; spm += p * fminf(da.w, db.w);
        }
        #pragma unroll
        for (int off = 32; off; off >>= 1) {
            sp += __shfl_xor(sp, off, 64);
            spm += __shfl_xor(spm, off, 64);
        }
        __syncthreads();
        if (lane == 0) { sA[wv] = sp; sB[wv] = spm; }
        __syncthreads();
        if (t == 0) {
            float a = 0.f, c2 = 0.f;
            #pragma unroll
            for (int i = 0; i < 16; i++) { a += sA[i]; c2 += sB[i]; }
            wsf[WS_SC + 3 + b] = a;
            wsf[WS_SC + 7 + b] = c2;
        }
    }
}

// ---------------- kC: reciprocal pass over packed columns (256 blocks x 32 rows) ----------------
__global__ __launch_bounds__(256) void whd_kC(const float* __restrict__ prob,
                                              float* __restrict__ wsf) {
    const int t = threadIdx.x;
    const int wv = t >> 6;              // batch of all 8 owned columns
    const int row0 = blockIdx.x * ROWS_C;
    const float* dpack = wsf + WS_DPACK;
    const float maxd = wsf[WS_SC + 0];
    const float pmin = wsf[WS_SC + 1];
    const float invr = 1.0f / wsf[WS_SC + 2];
    float acc[8];
    #pragma unroll
    for (int k = 0; k < 8; k++) acc[k] = 0.f;
    #pragma unroll 8
    for (int r = 0; r < ROWS_C; r++) {
        const int n = row0 + r;
        float p = (prob[wv * N_POS + n] - pmin) * invr;
        p = fminf(fmaxf(p, 0.f), 1.f);
        const f32x4* rp = (const f32x4*)(dpack + (size_t)n * BG + 8 * t);
        f32x4 v0 = rp[0];                // normal loads: dpack is LLC-resident
        f32x4 v1 = rp[1];
        acc[0] += 1.0f / (fmaf(p, v0.x - maxd, maxd) + EPSV);
        acc[1] += 1.0f / (fmaf(p, v0.y - maxd, maxd) + EPSV);
        acc[2] += 1.0f / (fmaf(p, v0.z - maxd, maxd) + EPSV);
        acc[3] += 1.0f / (fmaf(p, v0.w - maxd, maxd) + EPSV);
        acc[4] += 1.0f / (fmaf(p, v1.x - maxd, maxd) + EPSV);
        acc[5] += 1.0f / (fmaf(p, v1.y - maxd, maxd) + EPSV);
        acc[6] += 1.0f / (fmaf(p, v1.z - maxd, maxd) + EPSV);
        acc[7] += 1.0f / (fmaf(p, v1.w - maxd, maxd) + EPSV);
    }
    f32x4* op = (f32x4*)(wsf + WS_PARTS + (size_t)blockIdx.x * BG + 8 * t);
    f32x4 o0; o0.x = acc[0]; o0.y = acc[1]; o0.z = acc[2]; o0.w = acc[3];
    f32x4 o1; o1.x = acc[4]; o1.y = acc[5]; o1.z = acc[6]; o1.w = acc[7];
    op[0] = o0;
    op[1] = o1;
}

// ---------------- kD2: finish column sums -> term2, last block finalizes out ----------------
__global__ __launch_bounds__(256) void whd_kD2(float* __restrict__ wsf,
                                               float* __restrict__ out) {
    __shared__ float red[4];
    const int t = threadIdx.x;
    const int col = blockIdx.x * 256 + t;
    const float* parts = wsf + WS_PARTS;
    float s = 0.f;
    #pragma unroll 8
    for (int ch = 0; ch < KC_BLOCKS; ch++) s += parts[(size_t)ch * BG + col];
    float val = (float)N_POS / s;       // (mean_n 1/(w+eps))^-1
    #pragma unroll
    for (int off = 32; off; off >>= 1) val += __shfl_xor(val, off, 64);
    if ((t & 63) == 0) red[t >> 6] = val;
    __syncthreads();
    if (t == 0) {
        float blocksum = red[0] + red[1] + red[2] + red[3];
        atomicAdd(&wsf[WS_SC + 11], blocksum);
        __threadfence();
        unsigned prev = atomicAdd((unsigned*)(wsf + WS_SC + 12), 1u);
        if (prev == gridDim.x - 1) {
            float t2sum = atomicAdd(&wsf[WS_SC + 11], 0.0f);  // coherent read
            float term1 = 0.f;
            #pragma unroll
            for (int b = 0; b < BATCH; b++)
                term1 += wsf[WS_SC + 7 + b] / (wsf[WS_SC + 3 + b] + EPSV);
            out[0] = term1 * (1.0f / BATCH) + t2sum * (1.0f / BG);
        }
    }
}

extern "C" void kernel_launch(void* const* d_in, const int* in_sizes, int n_in,
                              void* d_out, int out_size, void* d_ws, size_t ws_size,
                              hipStream_t stream) {
    const float* prob = (const float*)d_in[0];   // (4, 8192) fp32
    const int* gt = (const int*)d_in[1];         // (4, 512) int32
    const float* dis = (const float*)d_in[2];    // (8192, 8192) fp32
    float* out = (float*)d_out;
    float* wsf = (float*)d_ws;

    whd_kA<<<KA_BLOCKS, 512, 0, stream>>>(dis, gt, wsf);
    whd_kB<<<1, 1024, 0, stream>>>(prob, wsf);
    whd_kC<<<KC_BLOCKS, 256, 0, stream>>>(prob, wsf);
    whd_kD2<<<BG / 256, 256, 0, stream>>>(wsf, out);
}